// Round 6
// baseline (153.662 us; speedup 1.0000x reference)
//
#include <hip/hip_runtime.h>
#include <hip/hip_fp16.h>

// PinPos: out[0:NP)      = pos[p2n[p]]             + pin_offset_x[p]
//         out[NP:2*NP)   = pos[num_nodes + p2n[p]] + pin_offset_y[p]
//
// R1: two 4B gathers/pin + stream eviction -> 287 MB fetch, 86 us.
// R3: float2 staging + NT streams -> 152 MB fetch, 50 us.
// R4: packed half2 staging (4 MB hot set fits 4 MiB L2/XCD) -> ~38 us.
// R5: 8 pins/thread -> near-neutral (~36 us): not simple latency-hiding.
// R6: 16 pins/thread, indices+gathers issued first — last test of the
//     latency-bound hypothesis. If neutral: L2 random-request service rate
//     is the structural floor (1 half2 gather/pin is already minimal).

typedef float nfloat4 __attribute__((ext_vector_type(4)));
typedef int   nint4   __attribute__((ext_vector_type(4)));
typedef unsigned int nuint4 __attribute__((ext_vector_type(4)));

__global__ __launch_bounds__(256) void interleave_h2_kernel(
    const float* __restrict__ pos,
    unsigned int* __restrict__ posh,   // packed half2 {x,y} per node
    int num_nodes)
{
    int i = blockIdx.x * blockDim.x + threadIdx.x;   // one thread = 4 nodes
    int base = i * 4;
    if (base + 3 < num_nodes) {
        nfloat4 x = *reinterpret_cast<const nfloat4*>(pos + base);
        nfloat4 y = *reinterpret_cast<const nfloat4*>(pos + num_nodes + base);
        __half2 h0 = __floats2half2_rn(x.x, y.x);
        __half2 h1 = __floats2half2_rn(x.y, y.y);
        __half2 h2 = __floats2half2_rn(x.z, y.z);
        __half2 h3 = __floats2half2_rn(x.w, y.w);
        nuint4 packed = { *reinterpret_cast<unsigned int*>(&h0),
                          *reinterpret_cast<unsigned int*>(&h1),
                          *reinterpret_cast<unsigned int*>(&h2),
                          *reinterpret_cast<unsigned int*>(&h3) };
        *reinterpret_cast<nuint4*>(posh + base) = packed;
    } else {
        for (int n = base; n < num_nodes; ++n) {
            __half2 h = __floats2half2_rn(pos[n], pos[num_nodes + n]);
            posh[n] = *reinterpret_cast<unsigned int*>(&h);
        }
    }
}

__global__ __launch_bounds__(256) void pinpos_h2x16_kernel(
    const __half2* __restrict__ posh,
    const float*   __restrict__ offx,
    const float*   __restrict__ offy,
    const int*     __restrict__ p2n,
    float*         __restrict__ out,
    int num_pins)
{
    int i = blockIdx.x * blockDim.x + threadIdx.x;   // one thread = 16 pins
    int base = i * 16;
    if (base + 15 < num_pins) {
        // 1) all index loads
        nint4 n0 = __builtin_nontemporal_load(reinterpret_cast<const nint4*>(p2n + base));
        nint4 n1 = __builtin_nontemporal_load(reinterpret_cast<const nint4*>(p2n + base + 4));
        nint4 n2 = __builtin_nontemporal_load(reinterpret_cast<const nint4*>(p2n + base + 8));
        nint4 n3 = __builtin_nontemporal_load(reinterpret_cast<const nint4*>(p2n + base + 12));

        // 2) all 16 gathers (issue as early as possible, stay in flight)
        __half2 g0  = posh[n0.x], g1  = posh[n0.y], g2  = posh[n0.z], g3  = posh[n0.w];
        __half2 g4  = posh[n1.x], g5  = posh[n1.y], g6  = posh[n1.z], g7  = posh[n1.w];
        __half2 g8  = posh[n2.x], g9  = posh[n2.y], g10 = posh[n2.z], g11 = posh[n2.w];
        __half2 g12 = posh[n3.x], g13 = posh[n3.y], g14 = posh[n3.z], g15 = posh[n3.w];

        // 3) offset streams (overlap gather service)
        nfloat4 ox0 = __builtin_nontemporal_load(reinterpret_cast<const nfloat4*>(offx + base));
        nfloat4 ox1 = __builtin_nontemporal_load(reinterpret_cast<const nfloat4*>(offx + base + 4));
        nfloat4 ox2 = __builtin_nontemporal_load(reinterpret_cast<const nfloat4*>(offx + base + 8));
        nfloat4 ox3 = __builtin_nontemporal_load(reinterpret_cast<const nfloat4*>(offx + base + 12));
        nfloat4 oy0 = __builtin_nontemporal_load(reinterpret_cast<const nfloat4*>(offy + base));
        nfloat4 oy1 = __builtin_nontemporal_load(reinterpret_cast<const nfloat4*>(offy + base + 4));
        nfloat4 oy2 = __builtin_nontemporal_load(reinterpret_cast<const nfloat4*>(offy + base + 8));
        nfloat4 oy3 = __builtin_nontemporal_load(reinterpret_cast<const nfloat4*>(offy + base + 12));

        float2 f0  = __half22float2(g0),  f1  = __half22float2(g1);
        float2 f2  = __half22float2(g2),  f3  = __half22float2(g3);
        float2 f4  = __half22float2(g4),  f5  = __half22float2(g5);
        float2 f6  = __half22float2(g6),  f7  = __half22float2(g7);
        float2 f8  = __half22float2(g8),  f9  = __half22float2(g9);
        float2 f10 = __half22float2(g10), f11 = __half22float2(g11);
        float2 f12 = __half22float2(g12), f13 = __half22float2(g13);
        float2 f14 = __half22float2(g14), f15 = __half22float2(g15);

        nfloat4 vx0 = { f0.x  + ox0.x, f1.x  + ox0.y, f2.x  + ox0.z, f3.x  + ox0.w };
        nfloat4 vx1 = { f4.x  + ox1.x, f5.x  + ox1.y, f6.x  + ox1.z, f7.x  + ox1.w };
        nfloat4 vx2 = { f8.x  + ox2.x, f9.x  + ox2.y, f10.x + ox2.z, f11.x + ox2.w };
        nfloat4 vx3 = { f12.x + ox3.x, f13.x + ox3.y, f14.x + ox3.z, f15.x + ox3.w };
        nfloat4 vy0 = { f0.y  + oy0.x, f1.y  + oy0.y, f2.y  + oy0.z, f3.y  + oy0.w };
        nfloat4 vy1 = { f4.y  + oy1.x, f5.y  + oy1.y, f6.y  + oy1.z, f7.y  + oy1.w };
        nfloat4 vy2 = { f8.y  + oy2.x, f9.y  + oy2.y, f10.y + oy2.z, f11.y + oy2.w };
        nfloat4 vy3 = { f12.y + oy3.x, f13.y + oy3.y, f14.y + oy3.z, f15.y + oy3.w };

        __builtin_nontemporal_store(vx0, reinterpret_cast<nfloat4*>(out + base));
        __builtin_nontemporal_store(vx1, reinterpret_cast<nfloat4*>(out + base + 4));
        __builtin_nontemporal_store(vx2, reinterpret_cast<nfloat4*>(out + base + 8));
        __builtin_nontemporal_store(vx3, reinterpret_cast<nfloat4*>(out + base + 12));
        float* outy = out + num_pins;
        __builtin_nontemporal_store(vy0, reinterpret_cast<nfloat4*>(outy + base));
        __builtin_nontemporal_store(vy1, reinterpret_cast<nfloat4*>(outy + base + 4));
        __builtin_nontemporal_store(vy2, reinterpret_cast<nfloat4*>(outy + base + 8));
        __builtin_nontemporal_store(vy3, reinterpret_cast<nfloat4*>(outy + base + 12));
    } else if (base < num_pins) {
        for (int p = base; p < num_pins; ++p) {
            float2 g = __half22float2(posh[p2n[p]]);
            out[p]            = g.x + offx[p];
            out[num_pins + p] = g.y + offy[p];
        }
    }
}

// Fallback (no workspace): direct two-gather fp32 version.
__global__ __launch_bounds__(256) void pinpos_direct_kernel(
    const float* __restrict__ pos,
    const float* __restrict__ offx,
    const float* __restrict__ offy,
    const int*   __restrict__ p2n,
    float*       __restrict__ out,
    int num_pins, int num_nodes)
{
    int i = blockIdx.x * blockDim.x + threadIdx.x;
    int base = i * 4;
    if (base + 3 < num_pins) {
        int4   n  = *reinterpret_cast<const int4*>(p2n + base);
        float4 ox = *reinterpret_cast<const float4*>(offx + base);
        float4 oy = *reinterpret_cast<const float4*>(offy + base);
        const float* posy = pos + num_nodes;
        float4 vx, vy;
        vx.x = pos[n.x] + ox.x;  vy.x = posy[n.x] + oy.x;
        vx.y = pos[n.y] + ox.y;  vy.y = posy[n.y] + oy.y;
        vx.z = pos[n.z] + ox.z;  vy.z = posy[n.z] + oy.z;
        vx.w = pos[n.w] + ox.w;  vy.w = posy[n.w] + oy.w;
        *reinterpret_cast<float4*>(out + base)            = vx;
        *reinterpret_cast<float4*>(out + num_pins + base) = vy;
    } else if (base < num_pins) {
        const float* posy = pos + num_nodes;
        for (int p = base; p < num_pins; ++p) {
            int n = p2n[p];
            out[p]            = pos[n]  + offx[p];
            out[num_pins + p] = posy[n] + offy[p];
        }
    }
}

extern "C" void kernel_launch(void* const* d_in, const int* in_sizes, int n_in,
                              void* d_out, int out_size, void* d_ws, size_t ws_size,
                              hipStream_t stream)
{
    const float* pos  = (const float*)d_in[0];
    const float* offx = (const float*)d_in[1];
    const float* offy = (const float*)d_in[2];
    const int*   p2n  = (const int*)d_in[3];

    int num_pins  = in_sizes[1];          // 4,000,000
    int num_nodes = in_sizes[0] / 2;      // 1,200,000
    float* out = (float*)d_out;

    const int block = 256;
    size_t need = (size_t)num_nodes * sizeof(unsigned int);   // 4.8 MB

    if (ws_size >= need) {
        unsigned int* posh = (unsigned int*)d_ws;
        int nthr = (num_nodes + 3) / 4;
        interleave_h2_kernel<<<(nthr + block - 1) / block, block, 0, stream>>>(
            pos, posh, num_nodes);
        int pthr = (num_pins + 15) / 16;
        pinpos_h2x16_kernel<<<(pthr + block - 1) / block, block, 0, stream>>>(
            (const __half2*)posh, offx, offy, p2n, out, num_pins);
    } else {
        int pthr = (num_pins + 3) / 4;
        pinpos_direct_kernel<<<(pthr + block - 1) / block, block, 0, stream>>>(
            pos, offx, offy, p2n, out, num_pins, num_nodes);
    }
}

// Round 7
// 142.754 us; speedup vs baseline: 1.0764x; 1.0764x over previous
//
#include <hip/hip_runtime.h>
#include <hip/hip_fp16.h>

// PinPos: out[0:NP)      = pos[p2n[p]]             + pin_offset_x[p]
//         out[NP:2*NP)   = pos[num_nodes + p2n[p]] + pin_offset_y[p]
//
// R1: two 4B gathers/pin + stream eviction -> 287 MB fetch, 86 us.
// R3: float2 staging + NT streams -> 152 MB fetch, 50 us.
// R4: packed half2 staging (4 MB hot set fits 4 MiB L2/XCD) -> ~37 us,
//     FETCH ~55 MB (near ideal) -> NOT HBM-bound anymore.
// R5: 8 pins/thread -> ~36 us (neutral: request pipe saturated).
// R6: 16 pins/thread REGRESSED (50 us): compiler allocated 36 VGPR ->
//     serialized the gather chain (no MLP) + grid down to 3.8 blocks/CU.
// R7: revert to 8 pins/thread + __launch_bounds__(256,2) for register
//     headroom. Floor model: 4M random line-requests / 256 CU x ~4.8 cyc
//     = ~36 us — per-CU vector-memory request rate, structural.

typedef float nfloat4 __attribute__((ext_vector_type(4)));
typedef int   nint4   __attribute__((ext_vector_type(4)));
typedef unsigned int nuint4 __attribute__((ext_vector_type(4)));

__global__ __launch_bounds__(256) void interleave_h2_kernel(
    const float* __restrict__ pos,
    unsigned int* __restrict__ posh,   // packed half2 {x,y} per node
    int num_nodes)
{
    int i = blockIdx.x * blockDim.x + threadIdx.x;   // one thread = 4 nodes
    int base = i * 4;
    if (base + 3 < num_nodes) {
        nfloat4 x = *reinterpret_cast<const nfloat4*>(pos + base);
        nfloat4 y = *reinterpret_cast<const nfloat4*>(pos + num_nodes + base);
        __half2 h0 = __floats2half2_rn(x.x, y.x);
        __half2 h1 = __floats2half2_rn(x.y, y.y);
        __half2 h2 = __floats2half2_rn(x.z, y.z);
        __half2 h3 = __floats2half2_rn(x.w, y.w);
        nuint4 packed = { *reinterpret_cast<unsigned int*>(&h0),
                          *reinterpret_cast<unsigned int*>(&h1),
                          *reinterpret_cast<unsigned int*>(&h2),
                          *reinterpret_cast<unsigned int*>(&h3) };
        *reinterpret_cast<nuint4*>(posh + base) = packed;
    } else {
        for (int n = base; n < num_nodes; ++n) {
            __half2 h = __floats2half2_rn(pos[n], pos[num_nodes + n]);
            posh[n] = *reinterpret_cast<unsigned int*>(&h);
        }
    }
}

__global__ __launch_bounds__(256, 2) void pinpos_h2x8_kernel(
    const __half2* __restrict__ posh,
    const float*   __restrict__ offx,
    const float*   __restrict__ offy,
    const int*     __restrict__ p2n,
    float*         __restrict__ out,
    int num_pins)
{
    int i = blockIdx.x * blockDim.x + threadIdx.x;   // one thread = 8 pins
    int base = i * 8;
    if (base + 7 < num_pins) {
        // Indices first so all 8 gathers issue early and overlap.
        nint4 n0 = __builtin_nontemporal_load(reinterpret_cast<const nint4*>(p2n + base));
        nint4 n1 = __builtin_nontemporal_load(reinterpret_cast<const nint4*>(p2n + base + 4));

        __half2 g0 = posh[n0.x];
        __half2 g1 = posh[n0.y];
        __half2 g2 = posh[n0.z];
        __half2 g3 = posh[n0.w];
        __half2 g4 = posh[n1.x];
        __half2 g5 = posh[n1.y];
        __half2 g6 = posh[n1.z];
        __half2 g7 = posh[n1.w];

        nfloat4 ox0 = __builtin_nontemporal_load(reinterpret_cast<const nfloat4*>(offx + base));
        nfloat4 ox1 = __builtin_nontemporal_load(reinterpret_cast<const nfloat4*>(offx + base + 4));
        nfloat4 oy0 = __builtin_nontemporal_load(reinterpret_cast<const nfloat4*>(offy + base));
        nfloat4 oy1 = __builtin_nontemporal_load(reinterpret_cast<const nfloat4*>(offy + base + 4));

        float2 f0 = __half22float2(g0);
        float2 f1 = __half22float2(g1);
        float2 f2 = __half22float2(g2);
        float2 f3 = __half22float2(g3);
        float2 f4 = __half22float2(g4);
        float2 f5 = __half22float2(g5);
        float2 f6 = __half22float2(g6);
        float2 f7 = __half22float2(g7);

        nfloat4 vx0 = { f0.x + ox0.x, f1.x + ox0.y, f2.x + ox0.z, f3.x + ox0.w };
        nfloat4 vx1 = { f4.x + ox1.x, f5.x + ox1.y, f6.x + ox1.z, f7.x + ox1.w };
        nfloat4 vy0 = { f0.y + oy0.x, f1.y + oy0.y, f2.y + oy0.z, f3.y + oy0.w };
        nfloat4 vy1 = { f4.y + oy1.x, f5.y + oy1.y, f6.y + oy1.z, f7.y + oy1.w };

        __builtin_nontemporal_store(vx0, reinterpret_cast<nfloat4*>(out + base));
        __builtin_nontemporal_store(vx1, reinterpret_cast<nfloat4*>(out + base + 4));
        __builtin_nontemporal_store(vy0, reinterpret_cast<nfloat4*>(out + num_pins + base));
        __builtin_nontemporal_store(vy1, reinterpret_cast<nfloat4*>(out + num_pins + base + 4));
    } else if (base < num_pins) {
        for (int p = base; p < num_pins; ++p) {
            float2 g = __half22float2(posh[p2n[p]]);
            out[p]            = g.x + offx[p];
            out[num_pins + p] = g.y + offy[p];
        }
    }
}

// Fallback (no workspace): direct two-gather fp32 version.
__global__ __launch_bounds__(256) void pinpos_direct_kernel(
    const float* __restrict__ pos,
    const float* __restrict__ offx,
    const float* __restrict__ offy,
    const int*   __restrict__ p2n,
    float*       __restrict__ out,
    int num_pins, int num_nodes)
{
    int i = blockIdx.x * blockDim.x + threadIdx.x;
    int base = i * 4;
    if (base + 3 < num_pins) {
        int4   n  = *reinterpret_cast<const int4*>(p2n + base);
        float4 ox = *reinterpret_cast<const float4*>(offx + base);
        float4 oy = *reinterpret_cast<const float4*>(offy + base);
        const float* posy = pos + num_nodes;
        float4 vx, vy;
        vx.x = pos[n.x] + ox.x;  vy.x = posy[n.x] + oy.x;
        vx.y = pos[n.y] + ox.y;  vy.y = posy[n.y] + oy.y;
        vx.z = pos[n.z] + ox.z;  vy.z = posy[n.z] + oy.z;
        vx.w = pos[n.w] + ox.w;  vy.w = posy[n.w] + oy.w;
        *reinterpret_cast<float4*>(out + base)            = vx;
        *reinterpret_cast<float4*>(out + num_pins + base) = vy;
    } else if (base < num_pins) {
        const float* posy = pos + num_nodes;
        for (int p = base; p < num_pins; ++p) {
            int n = p2n[p];
            out[p]            = pos[n]  + offx[p];
            out[num_pins + p] = posy[n] + offy[p];
        }
    }
}

extern "C" void kernel_launch(void* const* d_in, const int* in_sizes, int n_in,
                              void* d_out, int out_size, void* d_ws, size_t ws_size,
                              hipStream_t stream)
{
    const float* pos  = (const float*)d_in[0];
    const float* offx = (const float*)d_in[1];
    const float* offy = (const float*)d_in[2];
    const int*   p2n  = (const int*)d_in[3];

    int num_pins  = in_sizes[1];          // 4,000,000
    int num_nodes = in_sizes[0] / 2;      // 1,200,000
    float* out = (float*)d_out;

    const int block = 256;
    size_t need = (size_t)num_nodes * sizeof(unsigned int);   // 4.8 MB

    if (ws_size >= need) {
        unsigned int* posh = (unsigned int*)d_ws;
        int nthr = (num_nodes + 3) / 4;
        interleave_h2_kernel<<<(nthr + block - 1) / block, block, 0, stream>>>(
            pos, posh, num_nodes);
        int pthr = (num_pins + 7) / 8;
        pinpos_h2x8_kernel<<<(pthr + block - 1) / block, block, 0, stream>>>(
            (const __half2*)posh, offx, offy, p2n, out, num_pins);
    } else {
        int pthr = (num_pins + 3) / 4;
        pinpos_direct_kernel<<<(pthr + block - 1) / block, block, 0, stream>>>(
            pos, offx, offy, p2n, out, num_pins, num_nodes);
    }
}